// Round 6
// baseline (308.158 us; speedup 1.0000x reference)
//
#include <hip/hip_runtime.h>
#include <math.h>

// Problem constants
#define BATCH 2
#define HW 128          // H == W
#define CDIM 256
#define LTOK 16384      // HW*HW
#define MTOK 32768      // BATCH*LTOK
#define HEADS 8
#define DH 32
#define WINSZ 8
#define NWIN 64         // tokens per window
#define HID 1024

typedef unsigned int  u32;
typedef unsigned short u16;   // bf16 storage

typedef __attribute__((ext_vector_type(8))) short bf16x8;
typedef __attribute__((ext_vector_type(4))) float f32x4;

__device__ __forceinline__ float gelu_f(float v) {
    return 0.5f * v * (1.f + erff(v * 0.70710678118654752f));
}

__device__ __forceinline__ u16 f2bf(float f) {
    u32 u = __float_as_uint(f);
    u32 r = (u + 0x7fffu + ((u >> 16) & 1u)) >> 16;   // round-to-nearest-even
    return (u16)r;
}

// ---- generic 4-wide load/store: fp32 or bf16 ------------------------------
__device__ __forceinline__ float4 ld4(const float* p) { return *(const float4*)p; }
__device__ __forceinline__ float4 ld4(const u16* p) {
    uint2 v = *(const uint2*)p;
    float4 r;
    r.x = __uint_as_float((v.x & 0xffffu) << 16);
    r.y = __uint_as_float(v.x & 0xffff0000u);
    r.z = __uint_as_float((v.y & 0xffffu) << 16);
    r.w = __uint_as_float(v.y & 0xffff0000u);
    return r;
}
__device__ __forceinline__ void st4(float* p, float4 v) { *(float4*)p = v; }
__device__ __forceinline__ void st4(u16* p, float4 v) {
    uint2 o;
    o.x = (u32)f2bf(v.x) | ((u32)f2bf(v.y) << 16);
    o.y = (u32)f2bf(v.z) | ((u32)f2bf(v.w) << 16);
    *(uint2*)p = o;
}
// ---- scalar load/store ----------------------------------------------------
__device__ __forceinline__ float lds1(const float* p) { return *p; }
__device__ __forceinline__ float lds1(const u16* p) { return __uint_as_float(((u32)*p) << 16); }
__device__ __forceinline__ void sts1(float* p, float v) { *p = v; }
__device__ __forceinline__ void sts1(u16* p, float v) { *p = f2bf(v); }

// ---- 8-wide bf16 load -> 8 floats -----------------------------------------
__device__ __forceinline__ void ld8bf(const u16* p, float* v) {
    uint4 r = *(const uint4*)p;
    v[0] = __uint_as_float((r.x & 0xffffu) << 16);
    v[1] = __uint_as_float(r.x & 0xffff0000u);
    v[2] = __uint_as_float((r.y & 0xffffu) << 16);
    v[3] = __uint_as_float(r.y & 0xffff0000u);
    v[4] = __uint_as_float((r.z & 0xffffu) << 16);
    v[5] = __uint_as_float(r.z & 0xffff0000u);
    v[6] = __uint_as_float((r.w & 0xffffu) << 16);
    v[7] = __uint_as_float(r.w & 0xffff0000u);
}
// ---- 8 floats -> 8 bf16 packed store (16 B) -------------------------------
__device__ __forceinline__ void st8bf(u16* p, const float* v) {
    uint4 o;
    o.x = (u32)f2bf(v[0]) | ((u32)f2bf(v[1]) << 16);
    o.y = (u32)f2bf(v[2]) | ((u32)f2bf(v[3]) << 16);
    o.z = (u32)f2bf(v[4]) | ((u32)f2bf(v[5]) << 16);
    o.w = (u32)f2bf(v[6]) | ((u32)f2bf(v[7]) << 16);
    *(uint4*)p = o;
}
// ---- 16-wide typed load/store ---------------------------------------------
__device__ __forceinline__ void ldvec16(const float* p, float* v) {
    #pragma unroll
    for (int k = 0; k < 4; ++k) {
        float4 t = *(const float4*)(p + 4 * k);
        v[4*k] = t.x; v[4*k+1] = t.y; v[4*k+2] = t.z; v[4*k+3] = t.w;
    }
}
__device__ __forceinline__ void ldvec16(const u16* p, float* v) {
    ld8bf(p, v); ld8bf(p + 8, v + 8);
}
__device__ __forceinline__ void stvec16(float* p, const float* v) {
    #pragma unroll
    for (int k = 0; k < 4; ++k)
        *(float4*)(p + 4 * k) = make_float4(v[4*k], v[4*k+1], v[4*k+2], v[4*k+3]);
}
__device__ __forceinline__ void stvec16(u16* p, const float* v) {
    st8bf(p, v); st8bf(p + 8, v + 8);
}

// async global->LDS, 16B per lane (dest = wave-uniform base + lane*16)
__device__ __forceinline__ void glds16(const u16* g, u16* l) {
    __builtin_amdgcn_global_load_lds(
        (const __attribute__((address_space(1))) unsigned int*)g,
        (__attribute__((address_space(3))) unsigned int*)l, 16, 0, 0);
}

// ---------------------------------------------------------------------------
// Weight prep: fp32 [K][N] -> bf16 [N][K] (tiled LDS transpose, 32x32)
// ---------------------------------------------------------------------------
__global__ __launch_bounds__(256) void transpose_bf16_kernel(
    const float* __restrict__ in, u16* __restrict__ out, int K, int N)
{
    __shared__ float t[32][33];
    int bn = blockIdx.x * 32, bk = blockIdx.y * 32;
    int tx = threadIdx.x & 31, ty = threadIdx.x >> 5;   // 32 x 8
    #pragma unroll
    for (int i = 0; i < 32; i += 8)
        t[ty + i][tx] = in[(size_t)(bk + ty + i) * N + bn + tx];
    __syncthreads();
    #pragma unroll
    for (int i = 0; i < 32; i += 8)
        out[(size_t)(bn + ty + i) * K + bk + tx] = f2bf(t[tx][ty + i]);
}

// ---------------------------------------------------------------------------
// dw weight prep: [1024][9] fp32 -> [9][1024] fp32 (into d_out scratch)
// ---------------------------------------------------------------------------
__global__ __launch_bounds__(256) void dwprep_kernel(
    const float* __restrict__ in, float* __restrict__ out)
{
    int idx = blockIdx.x * 256 + threadIdx.x;   // 0..9215
    if (idx < 9 * HID) {
        int ch = idx / 9, t = idx - ch * 9;
        out[t * HID + ch] = in[idx];
    }
}

// ---------------------------------------------------------------------------
// LayerNorm over C=256: one wave (64 lanes) per row, 4 rows per 256-thr block
// ---------------------------------------------------------------------------
template<typename TI, typename TO>
__global__ __launch_bounds__(256) void ln_kernel(
    const TI* __restrict__ x, const float* __restrict__ g,
    const float* __restrict__ b, TO* __restrict__ y)
{
    int wave = threadIdx.x >> 6;
    int lane = threadIdx.x & 63;
    int row = blockIdx.x * 4 + wave;
    const TI* xr = x + (size_t)row * CDIM;
    float4 v = ld4(&xr[lane * 4]);
    float s  = v.x + v.y + v.z + v.w;
    float s2 = v.x*v.x + v.y*v.y + v.z*v.z + v.w*v.w;
    #pragma unroll
    for (int off = 32; off > 0; off >>= 1) {
        s  += __shfl_xor(s,  off);
        s2 += __shfl_xor(s2, off);
    }
    float mu   = s * (1.f / CDIM);
    float var  = s2 * (1.f / CDIM) - mu * mu;
    float rstd = rsqrtf(var + 1e-5f);
    float4 gv = *(const float4*)&g[lane * 4];
    float4 bv = *(const float4*)&b[lane * 4];
    float4 o;
    o.x = (v.x - mu) * rstd * gv.x + bv.x;
    o.y = (v.y - mu) * rstd * gv.y + bv.y;
    o.z = (v.z - mu) * rstd * gv.z + bv.z;
    o.w = (v.w - mu) * rstd * gv.w + bv.w;
    st4(&y[(size_t)row * CDIM + lane * 4], o);
}

// ---------------------------------------------------------------------------
// MFMA bf16 GEMM: C[M,N] = A[M,K](bf16) @ Bt[N,K](bf16)^T + bias (+res/+gelu)
// 128x128 tile, BK=32, 256 threads = 4 waves (2x2), each wave 64x64 via
// 4x4 fragments of mfma_f32_16x16x32_bf16. global_load_lds staging (m97).
// Epilogue: fp32 acc staged through LDS ([32][132] x 4 passes) so global
// stores are 16-element contiguous chunks (fixes 2x write amplification).
// EPI: 0 = bias, 1 = bias + residual, 2 = bias + GELU
// ---------------------------------------------------------------------------
template<int EPI, typename TR, typename TO>
__global__ __launch_bounds__(256) void mgemm_kernel(
    const u16* __restrict__ A, const u16* __restrict__ Bt,
    const float* __restrict__ bias, const TR* __restrict__ res,
    TO* __restrict__ Cc, int N, int K)
{
    // union: K-loop staging (16384 B) | epilogue tile 32x132 fp32 (16896 B)
    __shared__ __align__(16) char smem_raw[16896];
    u16*   smem = (u16*)smem_raw;
    float* eps  = (float*)smem_raw;
    const int EPAD = 132;

    int tid  = threadIdx.x;
    int lane = tid & 63;
    int wave = tid >> 6;
    int l15  = lane & 15;
    int hi   = lane >> 4;
    int wr = wave >> 1, wc = wave & 1;
    size_t bm = (size_t)blockIdx.y * 128;
    size_t bn = (size_t)blockIdx.x * 128;

    // staging source addresses (per lane): 16 rows per gload, 4 chunks/row
    int srow = wave * 32 + (lane >> 2);
    int scol = (lane & 3) * 8;
    const u16* ga = A  + (bm + srow) * K + scol;
    const u16* gb = Bt + (bn + srow) * K + scol;
    u16* laA0 = &smem[wave * 1024];
    u16* laA1 = &smem[wave * 1024 + 512];
    u16* laB0 = &smem[4096 + wave * 1024];
    u16* laB1 = &smem[4096 + wave * 1024 + 512];

    // fragment read offsets
    int ar = wr * 64 + l15;
    int br = wc * 64 + l15;
    int kc = hi * 8;

    f32x4 acc[4][4] = {};

    for (int kt = 0; kt < K; kt += 32) {
        glds16(ga, laA0);
        glds16(ga + 16 * K, laA1);
        glds16(gb, laB0);
        glds16(gb + 16 * K, laB1);
        ga += 32; gb += 32;
        __syncthreads();

        bf16x8 af[4], bfv[4];
        #pragma unroll
        for (int m = 0; m < 4; ++m)
            af[m] = *(const bf16x8*)&smem[(ar + m * 16) * 32 + kc];
        #pragma unroll
        for (int n = 0; n < 4; ++n)
            bfv[n] = *(const bf16x8*)&smem[4096 + (br + n * 16) * 32 + kc];
        #pragma unroll
        for (int m = 0; m < 4; ++m)
            #pragma unroll
            for (int n = 0; n < 4; ++n)
                acc[m][n] = __builtin_amdgcn_mfma_f32_16x16x32_bf16(
                    af[m], bfv[n], acc[m][n], 0, 0, 0);
        __syncthreads();
    }

    // ---- epilogue via LDS: 4 passes of 32 rows x 128 cols -----------------
    int lr  = tid >> 3;              // 0..31  LDS row (read phase)
    int cch = (tid & 7) * 16;        // 0..112 col chunk (read phase)
    #pragma unroll
    for (int m = 0; m < 4; ++m) {
        // write phase: C/D layout row = wr*64+m*16+hi*4+r, col = wc*64+n*16+l15
        #pragma unroll
        for (int n = 0; n < 4; ++n)
            #pragma unroll
            for (int r = 0; r < 4; ++r)
                eps[(wr * 16 + hi * 4 + r) * EPAD + wc * 64 + n * 16 + l15] =
                    acc[m][n][r];
        __syncthreads();
        // read phase: 16 contiguous cols per thread, coalesced global store
        int grow = (int)bm + (lr >> 4) * 64 + m * 16 + (lr & 15);
        int gcol = (int)bn + cch;
        float t16[16];
        ldvec16(&eps[lr * EPAD + cch], t16);
        float rv[16];
        if (EPI == 1) ldvec16(&res[(size_t)grow * N + gcol], rv);
        #pragma unroll
        for (int k = 0; k < 16; ++k) {
            float v = t16[k] + bias[gcol + k];
            if (EPI == 1) v += rv[k];
            if (EPI == 2) v = gelu_f(v);
            t16[k] = v;
        }
        stvec16(&Cc[(size_t)grow * N + gcol], t16);
        __syncthreads();
    }
}

// ---------------------------------------------------------------------------
// MFMA windowed attention: one 64-thread wave per (window, head).
// QK^T (64x64x32) and PV (64x32x64) via mfma_f32_16x16x32_bf16.
// Q/K/V fragments load directly from global qkv (shifted-window gather).
// Softmax in C/D register layout; P routed through XOR-swizzled LDS.
// ---------------------------------------------------------------------------
__global__ __launch_bounds__(64) void attn_mfma_kernel(
    const u16* __restrict__ qkv, const float* __restrict__ bias_table,
    u16* __restrict__ out)
{
    __shared__ u16 P[NWIN * NWIN];   // [64 q][64 k] bf16, col ^= (row&7)<<3
    __shared__ int lbl[NWIN];

    int lane = threadIdx.x;
    int l15 = lane & 15;
    int hi  = lane >> 4;
    int widx = blockIdx.x;           // 0..511  (b*256 + wr*16 + wc)
    int head = blockIdx.y;           // 0..7
    int b  = widx >> 8;
    int w  = widx & 255;
    int wr = w >> 4, wc = w & 15;

    // window token n -> global token index (shift roll by +4 with wrap)
    auto tokof = [&](int n) -> int {
        int si = (wr * WINSZ + (n >> 3) + 4) & 127;
        int sj = (wc * WINSZ + (n & 7) + 4) & 127;
        return b * LTOK + si * HW + sj;
    };

    // labels (mask regions) in shifted coords
    {
        int i = wr * WINSZ + (lane >> 3);
        int j = wc * WINSZ + (lane & 7);
        int li = (i < 120) ? 0 : (i < 124 ? 1 : 2);
        int lj = (j < 120) ? 0 : (j < 124 ? 1 : 2);
        lbl[lane] = li * 3 + lj;
    }

    // ---- load Q & K fragments directly from global -------------------------
    // A/B-frag layout: row = frag*16 + (lane&15), k = (lane>>4)*8 + i
    bf16x8 qf[4], kf[4];
    #pragma unroll
    for (int m = 0; m < 4; ++m) {
        int t = tokof(m * 16 + l15);
        const u16* base = qkv + (size_t)t * 768 + head * DH + hi * 8;
        qf[m] = *(const bf16x8*)base;           // q slice
        kf[m] = *(const bf16x8*)(base + 256);   // k slice
    }

    // ---- gather V^T B-fragments: vf[nf][ks], lane holds d=nf*16+l15,
    //      keys k = ks*32 + hi*8 + i -------------------------------------
    bf16x8 vf[2][2];
    #pragma unroll
    for (int ks = 0; ks < 2; ++ks) {
        #pragma unroll
        for (int i = 0; i < 8; ++i) {
            int t = tokof(ks * 32 + hi * 8 + i);
            const u16* vb = qkv + (size_t)t * 768 + 512 + head * DH;
            vf[0][ks][i] = (short)vb[l15];
            vf[1][ks][i] = (short)vb[16 + l15];
        }
    }

    // ---- QK^T: S[q][k], fragments s[m][n] ---------------------------------
    f32x4 s[4][4];
    #pragma unroll
    for (int m = 0; m < 4; ++m)
        #pragma unroll
        for (int n = 0; n < 4; ++n) {
            f32x4 z = {0.f, 0.f, 0.f, 0.f};
            s[m][n] = __builtin_amdgcn_mfma_f32_16x16x32_bf16(qf[m], kf[n], z, 0, 0, 0);
        }

    __syncthreads();   // lbl visible

    // k-token labels for this lane's columns
    int klbl[4];
    #pragma unroll
    for (int n = 0; n < 4; ++n) klbl[n] = lbl[n * 16 + l15];

    // ---- softmax in C/D layout: row q = m*16+hi*4+r, col k = n*16+l15 -----
    const float SCALE = 0.17677669529663687f;  // 1/sqrt(32)
    float inv[4][4];
    #pragma unroll
    for (int m = 0; m < 4; ++m) {
        #pragma unroll
        for (int r = 0; r < 4; ++r) {
            int q = m * 16 + hi * 4 + r;
            int qlbl = lbl[q];
            int rq = q >> 3, cq = q & 7;
            float v[4];
            #pragma unroll
            for (int n = 0; n < 4; ++n) {
                int kn = n * 16 + l15;
                int idx = (rq - (kn >> 3) + 7) * 15 + (cq - (kn & 7) + 7);
                float bv = bias_table[idx * HEADS + head];
                v[n] = s[m][n][r] * SCALE + bv + ((klbl[n] != qlbl) ? -100.f : 0.f);
            }
            float rmax = fmaxf(fmaxf(v[0], v[1]), fmaxf(v[2], v[3]));
            #pragma unroll
            for (int off = 1; off < 16; off <<= 1)
                rmax = fmaxf(rmax, __shfl_xor(rmax, off));
            float p0 = __expf(v[0] - rmax), p1 = __expf(v[1] - rmax);
            float p2 = __expf(v[2] - rmax), p3 = __expf(v[3] - rmax);
            float ls = p0 + p1 + p2 + p3;
            #pragma unroll
            for (int off = 1; off < 16; off <<= 1)
                ls += __shfl_xor(ls, off);
            inv[m][r] = 1.f / ls;
            int sw = (q & 7) << 3;
            P[q * NWIN + ((0 * 16 + l15) ^ sw)] = f2bf(p0);
            P[q * NWIN + ((1 * 16 + l15) ^ sw)] = f2bf(p1);
            P[q * NWIN + ((2 * 16 + l15) ^ sw)] = f2bf(p2);
            P[q * NWIN + ((3 * 16 + l15) ^ sw)] = f2bf(p3);
        }
    }

    __syncthreads();   // P visible

    // ---- PV: O[q][d] = P @ V, acc o[m][nf] --------------------------------
    f32x4 o[4][2] = {};
    #pragma unroll
    for (int ks = 0; ks < 2; ++ks) {
        #pragma unroll
        for (int m = 0; m < 4; ++m) {
            int row = m * 16 + l15;
            int colb = (ks * 32 + hi * 8) ^ ((row & 7) << 3);
            bf16x8 pa = *(const bf16x8*)&P[row * NWIN + colb];
            #pragma unroll
            for (int nf = 0; nf < 2; ++nf)
                o[m][nf] = __builtin_amdgcn_mfma_f32_16x16x32_bf16(
                    pa, vf[nf][ks], o[m][nf], 0, 0, 0);
        }
    }

    // ---- epilogue: normalize rows, scatter to out -------------------------
    #pragma unroll
    for (int m = 0; m < 4; ++m) {
        #pragma unroll
        for (int r = 0; r < 4; ++r) {
            int q = m * 16 + hi * 4 + r;
            int t = tokof(q);
            u16* op = out + (size_t)t * CDIM + head * DH + l15;
            float iv = inv[m][r];
            op[0]  = f2bf(o[m][0][r] * iv);
            op[16] = f2bf(o[m][1][r] * iv);
        }
    }
}

// ---------------------------------------------------------------------------
// Depthwise 3x3 conv (NHWC, SAME zero-pad) + bias + GELU. bf16 in/out.
// Thread: 8 channels x 4 consecutive pixels along j (16B loads, j-overlap
// reuse: 18 row-loads for 4 outputs). Block: 8 pixels x 1024 ch. Grid 4096.
// wt9: [9][1024] fp32 tap-major table (pre-transposed, lives in d_out scratch)
// ---------------------------------------------------------------------------
__global__ __launch_bounds__(256) void dwconv_kernel(
    const u16* __restrict__ h, const float* __restrict__ wt9,
    const float* __restrict__ bias, u16* __restrict__ out)
{
    int blk = blockIdx.x;             // b*2048 + i*16 + jt
    int b   = blk >> 11;
    int rem = blk & 2047;
    int i   = rem >> 4;
    int jt  = rem & 15;
    int cg  = (threadIdx.x & 127) * 8;           // channel base (0..1016)
    int j0  = jt * 8 + (threadIdx.x >> 7) * 4;   // first of 4 output pixels

    float acc[4][8] = {};
    const u16* base = h + (size_t)b * LTOK * HID + cg;

    #pragma unroll
    for (int di = 0; di < 3; ++di) {
        int ii = i + di - 1;
        if (ii < 0 || ii >= HW) continue;
        const u16* rowp = base + (size_t)ii * HW * HID;
        float v[6][8];
        #pragma unroll
        for (int cc = 0; cc < 6; ++cc) {
            int jj = j0 - 1 + cc;
            if (jj >= 0 && jj < HW) {
                ld8bf(&rowp[(size_t)jj * HID], v[cc]);
            } else {
                #pragma unroll
                for (int q = 0; q < 8; ++q) v[cc][q] = 0.f;
            }
        }
        #pragma unroll
        for (int t = 0; t < 3; ++t) {
            const float* wp = &wt9[(di * 3 + t) * HID + cg];
            float4 wa = *(const float4*)wp;
            float4 wb = *(const float4*)(wp + 4);
            float w[8] = {wa.x, wa.y, wa.z, wa.w, wb.x, wb.y, wb.z, wb.w};
            #pragma unroll
            for (int p = 0; p < 4; ++p)
                #pragma unroll
                for (int q = 0; q < 8; ++q)
                    acc[p][q] += v[p + t][q] * w[q];
        }
    }

    float4 ba = *(const float4*)&bias[cg];
    float4 bb = *(const float4*)&bias[cg + 4];
    float bs[8] = {ba.x, ba.y, ba.z, ba.w, bb.x, bb.y, bb.z, bb.w};
    u16* ob = out + ((size_t)b * LTOK + (size_t)i * HW + j0) * HID + cg;
    #pragma unroll
    for (int p = 0; p < 4; ++p) {
        u32 o[4];
        #pragma unroll
        for (int q = 0; q < 4; ++q) {
            u16 lo = f2bf(gelu_f(acc[p][2 * q] + bs[2 * q]));
            u16 hi = f2bf(gelu_f(acc[p][2 * q + 1] + bs[2 * q + 1]));
            o[q] = (u32)lo | ((u32)hi << 16);
        }
        *(uint4*)(ob + (size_t)p * HID) = make_uint4(o[0], o[1], o[2], o[3]);
    }
}

// ---------------------------------------------------------------------------
extern "C" void kernel_launch(void* const* d_in, const int* in_sizes, int n_in,
                              void* d_out, int out_size, void* d_ws, size_t ws_size,
                              hipStream_t stream) {
    const float* x      = (const float*)d_in[0];
    const float* n1g    = (const float*)d_in[1];
    const float* n1b    = (const float*)d_in[2];
    const float* qkv_w  = (const float*)d_in[3];
    const float* qkv_b  = (const float*)d_in[4];
    const float* relb   = (const float*)d_in[5];
    const float* proj_w = (const float*)d_in[6];
    const float* proj_b = (const float*)d_in[7];
    const float* n2g    = (const float*)d_in[8];
    const float* n2b    = (const float*)d_in[9];
    const float* lin1_w = (const float*)d_in[10];
    const float* lin1_b = (const float*)d_in[11];
    const float* dw_w   = (const float*)d_in[12];
    const float* dw_b   = (const float*)d_in[13];
    const float* lin2_w = (const float*)d_in[14];
    const float* lin2_b = (const float*)d_in[15];
    float* out = (float*)d_out;

    // bf16 arena (9*M8 elems = 151 MB, same as passing round 5):
    //  R0 [0,4M8):   yn -> attn -> yn2 -> h2[0:4M8)
    //  R1 [M8,4M8):  qkv -> lin1_wt
    //  R2 [4M8,5M8): x1 (steps 4-8)
    //  R3 [5M8,9M8): qkv_wt+proj_wt (steps 0-4) -> hbuf (6-7) -> lin2_wt (8)
    u16* ws16 = (u16*)d_ws;
    const size_t M8 = (size_t)MTOK * CDIM;   // 8,388,608
    u16* yn      = ws16;
    u16* qkv     = ws16 + M8;
    u16* attn    = ws16;
    u16* x1      = ws16 + 4 * M8;
    u16* yn2     = ws16;
    u16* hbuf    = ws16 + 5 * M8;
    u16* h2      = ws16;
    u16* qkv_wt  = ws16 + 5 * M8;            // [768][256]
    u16* proj_wt = qkv_wt + 768 * 256;       // [256][256]
    u16* lin1_wt = ws16 + M8;                // [1024][256]
    u16* lin2_wt = ws16 + 5 * M8;            // [256][1024]
    float* wt9   = (float*)d_out;            // [9][1024] scratch; d_out dead
                                             // until step 8 fully overwrites it

    // 0) weight prep (qkv, proj)
    transpose_bf16_kernel<<<dim3(768 / 32, 256 / 32), 256, 0, stream>>>(qkv_w, qkv_wt, 256, 768);
    transpose_bf16_kernel<<<dim3(256 / 32, 256 / 32), 256, 0, stream>>>(proj_w, proj_wt, 256, 256);
    // 1) LN1: fp32 in, bf16 out
    ln_kernel<float, u16><<<MTOK / 4, 256, 0, stream>>>(x, n1g, n1b, yn);
    // 2) qkv = yn @ qkv_w + qkv_b
    mgemm_kernel<0, float, u16><<<dim3(768 / 128, MTOK / 128), 256, 0, stream>>>(
        yn, qkv_wt, qkv_b, (const float*)nullptr, qkv, 768, CDIM);
    // 3) windowed attention (MFMA)
    attn_mfma_kernel<<<dim3(512, HEADS), 64, 0, stream>>>(qkv, relb, attn);
    // weight prep (lin1) into R1 (qkv now dead); dw weights into d_out scratch
    transpose_bf16_kernel<<<dim3(1024 / 32, 256 / 32), 256, 0, stream>>>(lin1_w, lin1_wt, 256, 1024);
    dwprep_kernel<<<36, 256, 0, stream>>>(dw_w, wt9);
    // 4) x1 = attn @ proj_w + proj_b + x
    mgemm_kernel<1, float, u16><<<dim3(CDIM / 128, MTOK / 128), 256, 0, stream>>>(
        attn, proj_wt, proj_b, x, x1, CDIM, CDIM);
    // 5) LN2: bf16 in, bf16 out
    ln_kernel<u16, u16><<<MTOK / 4, 256, 0, stream>>>(x1, n2g, n2b, yn2);
    // 6) hbuf = gelu(yn2 @ lin1_w + lin1_b)
    mgemm_kernel<2, float, u16><<<dim3(HID / 128, MTOK / 128), 256, 0, stream>>>(
        yn2, lin1_wt, lin1_b, (const float*)nullptr, hbuf, HID, CDIM);
    // 7) h2 = gelu(dwconv3x3(hbuf) + dw_b)
    dwconv_kernel<<<BATCH * 2048, 256, 0, stream>>>(hbuf, wt9, dw_b, h2);
    // weight prep (lin2) into R3 (hbuf now dead)
    transpose_bf16_kernel<<<dim3(256 / 32, 1024 / 32), 256, 0, stream>>>(lin2_w, lin2_wt, 1024, 256);
    // 8) out = h2 @ lin2_w + lin2_b + x1   (fp32 out)
    mgemm_kernel<1, u16, float><<<dim3(CDIM / 128, MTOK / 128), 256, 0, stream>>>(
        h2, lin2_wt, lin2_b, x1, out, CDIM, HID);

    (void)in_sizes; (void)n_in; (void)out_size; (void)ws_size;
}

// Round 7
// 305.224 us; speedup vs baseline: 1.0096x; 1.0096x over previous
//
#include <hip/hip_runtime.h>
#include <math.h>

// Problem constants
#define BATCH 2
#define HW 128          // H == W
#define CDIM 256
#define LTOK 16384      // HW*HW
#define MTOK 32768      // BATCH*LTOK
#define HEADS 8
#define DH 32
#define WINSZ 8
#define NWIN 64         // tokens per window
#define HID 1024

typedef unsigned int  u32;
typedef unsigned short u16;   // bf16 storage

typedef __attribute__((ext_vector_type(8))) short bf16x8;
typedef __attribute__((ext_vector_type(4))) float f32x4;

__device__ __forceinline__ float gelu_f(float v) {
    return 0.5f * v * (1.f + erff(v * 0.70710678118654752f));
}

__device__ __forceinline__ u16 f2bf(float f) {
    u32 u = __float_as_uint(f);
    u32 r = (u + 0x7fffu + ((u >> 16) & 1u)) >> 16;   // round-to-nearest-even
    return (u16)r;
}

// ---- generic 4-wide load/store: fp32 or bf16 ------------------------------
__device__ __forceinline__ float4 ld4(const float* p) { return *(const float4*)p; }
__device__ __forceinline__ float4 ld4(const u16* p) {
    uint2 v = *(const uint2*)p;
    float4 r;
    r.x = __uint_as_float((v.x & 0xffffu) << 16);
    r.y = __uint_as_float(v.x & 0xffff0000u);
    r.z = __uint_as_float((v.y & 0xffffu) << 16);
    r.w = __uint_as_float(v.y & 0xffff0000u);
    return r;
}
__device__ __forceinline__ void st4(float* p, float4 v) { *(float4*)p = v; }
__device__ __forceinline__ void st4(u16* p, float4 v) {
    uint2 o;
    o.x = (u32)f2bf(v.x) | ((u32)f2bf(v.y) << 16);
    o.y = (u32)f2bf(v.z) | ((u32)f2bf(v.w) << 16);
    *(uint2*)p = o;
}
// ---- scalar load/store ----------------------------------------------------
__device__ __forceinline__ float lds1(const float* p) { return *p; }
__device__ __forceinline__ float lds1(const u16* p) { return __uint_as_float(((u32)*p) << 16); }
__device__ __forceinline__ void sts1(float* p, float v) { *p = v; }
__device__ __forceinline__ void sts1(u16* p, float v) { *p = f2bf(v); }

// ---- 8-wide bf16 load -> 8 floats -----------------------------------------
__device__ __forceinline__ void ld8bf(const u16* p, float* v) {
    uint4 r = *(const uint4*)p;
    v[0] = __uint_as_float((r.x & 0xffffu) << 16);
    v[1] = __uint_as_float(r.x & 0xffff0000u);
    v[2] = __uint_as_float((r.y & 0xffffu) << 16);
    v[3] = __uint_as_float(r.y & 0xffff0000u);
    v[4] = __uint_as_float((r.z & 0xffffu) << 16);
    v[5] = __uint_as_float(r.z & 0xffff0000u);
    v[6] = __uint_as_float((r.w & 0xffffu) << 16);
    v[7] = __uint_as_float(r.w & 0xffff0000u);
}
// ---- 8 floats -> 8 bf16 packed store (16 B) -------------------------------
__device__ __forceinline__ void st8bf(u16* p, const float* v) {
    uint4 o;
    o.x = (u32)f2bf(v[0]) | ((u32)f2bf(v[1]) << 16);
    o.y = (u32)f2bf(v[2]) | ((u32)f2bf(v[3]) << 16);
    o.z = (u32)f2bf(v[4]) | ((u32)f2bf(v[5]) << 16);
    o.w = (u32)f2bf(v[6]) | ((u32)f2bf(v[7]) << 16);
    *(uint4*)p = o;
}
// ---- 16-wide typed load/store ---------------------------------------------
__device__ __forceinline__ void ldvec16(const float* p, float* v) {
    #pragma unroll
    for (int k = 0; k < 4; ++k) {
        float4 t = *(const float4*)(p + 4 * k);
        v[4*k] = t.x; v[4*k+1] = t.y; v[4*k+2] = t.z; v[4*k+3] = t.w;
    }
}
__device__ __forceinline__ void ldvec16(const u16* p, float* v) {
    ld8bf(p, v); ld8bf(p + 8, v + 8);
}
__device__ __forceinline__ void stvec16(float* p, const float* v) {
    #pragma unroll
    for (int k = 0; k < 4; ++k)
        *(float4*)(p + 4 * k) = make_float4(v[4*k], v[4*k+1], v[4*k+2], v[4*k+3]);
}
__device__ __forceinline__ void stvec16(u16* p, const float* v) {
    st8bf(p, v); st8bf(p + 8, v + 8);
}

// async global->LDS, 16B per lane (dest = wave-uniform base + lane*16)
__device__ __forceinline__ void glds16(const u16* g, u16* l) {
    __builtin_amdgcn_global_load_lds(
        (const __attribute__((address_space(1))) unsigned int*)g,
        (__attribute__((address_space(3))) unsigned int*)l, 16, 0, 0);
}

// ---------------------------------------------------------------------------
// Weight prep: fp32 [K][N] -> bf16 [N][K] (tiled LDS transpose, 32x32)
// ---------------------------------------------------------------------------
__global__ __launch_bounds__(256) void transpose_bf16_kernel(
    const float* __restrict__ in, u16* __restrict__ out, int K, int N)
{
    __shared__ float t[32][33];
    int bn = blockIdx.x * 32, bk = blockIdx.y * 32;
    int tx = threadIdx.x & 31, ty = threadIdx.x >> 5;   // 32 x 8
    #pragma unroll
    for (int i = 0; i < 32; i += 8)
        t[ty + i][tx] = in[(size_t)(bk + ty + i) * N + bn + tx];
    __syncthreads();
    #pragma unroll
    for (int i = 0; i < 32; i += 8)
        out[(size_t)(bn + ty + i) * K + bk + tx] = f2bf(t[tx][ty + i]);
}

// ---------------------------------------------------------------------------
// dw weight prep: [1024][9] fp32 -> [9][1024] fp32 (into d_out scratch)
// ---------------------------------------------------------------------------
__global__ __launch_bounds__(256) void dwprep_kernel(
    const float* __restrict__ in, float* __restrict__ out)
{
    int idx = blockIdx.x * 256 + threadIdx.x;   // 0..9215
    if (idx < 9 * HID) {
        int ch = idx / 9, t = idx - ch * 9;
        out[t * HID + ch] = in[idx];
    }
}

// ---------------------------------------------------------------------------
// LayerNorm over C=256: one wave (64 lanes) per row, 4 rows per 256-thr block
// ---------------------------------------------------------------------------
template<typename TI, typename TO>
__global__ __launch_bounds__(256) void ln_kernel(
    const TI* __restrict__ x, const float* __restrict__ g,
    const float* __restrict__ b, TO* __restrict__ y)
{
    int wave = threadIdx.x >> 6;
    int lane = threadIdx.x & 63;
    int row = blockIdx.x * 4 + wave;
    const TI* xr = x + (size_t)row * CDIM;
    float4 v = ld4(&xr[lane * 4]);
    float s  = v.x + v.y + v.z + v.w;
    float s2 = v.x*v.x + v.y*v.y + v.z*v.z + v.w*v.w;
    #pragma unroll
    for (int off = 32; off > 0; off >>= 1) {
        s  += __shfl_xor(s,  off);
        s2 += __shfl_xor(s2, off);
    }
    float mu   = s * (1.f / CDIM);
    float var  = s2 * (1.f / CDIM) - mu * mu;
    float rstd = rsqrtf(var + 1e-5f);
    float4 gv = *(const float4*)&g[lane * 4];
    float4 bv = *(const float4*)&b[lane * 4];
    float4 o;
    o.x = (v.x - mu) * rstd * gv.x + bv.x;
    o.y = (v.y - mu) * rstd * gv.y + bv.y;
    o.z = (v.z - mu) * rstd * gv.z + bv.z;
    o.w = (v.w - mu) * rstd * gv.w + bv.w;
    st4(&y[(size_t)row * CDIM + lane * 4], o);
}

// ---------------------------------------------------------------------------
// MFMA bf16 GEMM: C[M,N] = A[M,K](bf16) @ Bt[N,K](bf16)^T + bias (+res/+gelu)
// 128x128 tile, BK=32, 256 threads = 4 waves (2x2), each wave 64x64 via
// 4x4 fragments of mfma_f32_16x16x32_bf16.
// v3: double-buffered global_load_lds staging (stage t+1 overlaps MFMA t,
// one barrier per K-step) + XCD-bijective block swizzle (1-D grid, nwg%8==0).
// Epilogue: fp32 acc through LDS (2 passes of 64x132), coalesced stores.
// EPI: 0 = bias, 1 = bias + residual, 2 = bias + GELU
// ---------------------------------------------------------------------------
template<int EPI, typename TR, typename TO>
__global__ __launch_bounds__(256) void mgemm_kernel(
    const u16* __restrict__ A, const u16* __restrict__ Bt,
    const float* __restrict__ bias, const TR* __restrict__ res,
    TO* __restrict__ Cc, int N, int K, int gx)
{
    // union: dbuf staging 2 x 16384 B | epilogue tile 64x132 fp32 (33792 B)
    __shared__ __align__(16) char smem_raw[34816];
    u16*   smem = (u16*)smem_raw;
    float* eps  = (float*)smem_raw;

    int tid  = threadIdx.x;
    int lane = tid & 63;
    int wave = tid >> 6;
    int l15  = lane & 15;
    int hi   = lane >> 4;
    int wr = wave >> 1, wc = wave & 1;

    // XCD-bijective swizzle: blocks sharing an A-panel land on one XCD
    int nwg = gridDim.x;
    int bid = blockIdx.x;
    int swz = (bid & 7) * (nwg >> 3) + (bid >> 3);
    int bx = swz % gx, by = swz / gx;
    size_t bm = (size_t)by * 128;
    size_t bn = (size_t)bx * 128;

    // staging source addresses (per lane): 16 rows per gload, 4 chunks/row
    int srow = wave * 32 + (lane >> 2);
    int scol = (lane & 3) * 8;
    const u16* ga = A  + (bm + srow) * K + scol;
    const u16* gb = Bt + (bn + srow) * K + scol;

    // fragment read offsets
    int ar = wr * 64 + l15;
    int br = wc * 64 + l15;
    int kc = hi * 8;

    f32x4 acc[4][4] = {};
    int nt = K >> 5;

    // prologue: stage tile 0 into buf 0
    {
        u16* d = smem + wave * 1024;
        glds16(ga, d);
        glds16(ga + 16 * K, d + 512);
        glds16(gb, d + 4096);
        glds16(gb + 16 * K, d + 4096 + 512);
        ga += 32; gb += 32;
    }
    __syncthreads();

    int cur = 0;
    for (int t = 0; t < nt; ++t) {
        if (t + 1 < nt) {
            u16* d = smem + (cur ^ 1) * 8192 + wave * 1024;
            glds16(ga, d);
            glds16(ga + 16 * K, d + 512);
            glds16(gb, d + 4096);
            glds16(gb + 16 * K, d + 4096 + 512);
            ga += 32; gb += 32;
        }
        const u16* sb = smem + cur * 8192;
        bf16x8 af[4], bfv[4];
        #pragma unroll
        for (int m = 0; m < 4; ++m)
            af[m] = *(const bf16x8*)&sb[(ar + m * 16) * 32 + kc];
        #pragma unroll
        for (int n = 0; n < 4; ++n)
            bfv[n] = *(const bf16x8*)&sb[4096 + (br + n * 16) * 32 + kc];
        #pragma unroll
        for (int m = 0; m < 4; ++m)
            #pragma unroll
            for (int n = 0; n < 4; ++n)
                acc[m][n] = __builtin_amdgcn_mfma_f32_16x16x32_bf16(
                    af[m], bfv[n], acc[m][n], 0, 0, 0);
        __syncthreads();
        cur ^= 1;
    }

    // ---- epilogue via LDS: 2 passes of 64 eps-rows x 128 cols -------------
    // pass p covers fragments m = {2p, 2p+1}; eps row = wr*32+mm*16+hi*4+r
    int er  = tid >> 2;              // 0..63
    int cch = (tid & 3) * 32;        // 0,32,64,96
    #pragma unroll
    for (int p = 0; p < 2; ++p) {
        #pragma unroll
        for (int mm = 0; mm < 2; ++mm) {
            int m = p * 2 + mm;
            #pragma unroll
            for (int n = 0; n < 4; ++n)
                #pragma unroll
                for (int r = 0; r < 4; ++r)
                    eps[(wr * 32 + mm * 16 + hi * 4 + r) * 132 +
                        wc * 64 + n * 16 + l15] = acc[m][n][r];
        }
        __syncthreads();
        int grow = (int)bm + (er >> 5) * 64 + p * 32 + (er & 31);
        int gcol = (int)bn + cch;
        float t32[32];
        #pragma unroll
        for (int k = 0; k < 8; ++k) {
            float4 v = *(const float4*)&eps[er * 132 + cch + 4 * k];
            t32[4*k] = v.x; t32[4*k+1] = v.y; t32[4*k+2] = v.z; t32[4*k+3] = v.w;
        }
        float rv[32];
        if (EPI == 1) {
            ldvec16(&res[(size_t)grow * N + gcol], rv);
            ldvec16(&res[(size_t)grow * N + gcol + 16], rv + 16);
        }
        #pragma unroll
        for (int k = 0; k < 32; ++k) {
            float v = t32[k] + bias[gcol + k];
            if (EPI == 1) v += rv[k];
            if (EPI == 2) v = gelu_f(v);
            t32[k] = v;
        }
        stvec16(&Cc[(size_t)grow * N + gcol], t32);
        stvec16(&Cc[(size_t)grow * N + gcol + 16], t32 + 16);
        __syncthreads();
    }
}

// ---------------------------------------------------------------------------
// MFMA windowed attention: one 64-thread wave per (window, head).
// ---------------------------------------------------------------------------
__global__ __launch_bounds__(64) void attn_mfma_kernel(
    const u16* __restrict__ qkv, const float* __restrict__ bias_table,
    u16* __restrict__ out)
{
    __shared__ u16 P[NWIN * NWIN];   // [64 q][64 k] bf16, col ^= (row&7)<<3
    __shared__ int lbl[NWIN];

    int lane = threadIdx.x;
    int l15 = lane & 15;
    int hi  = lane >> 4;
    int widx = blockIdx.x;           // 0..511  (b*256 + wr*16 + wc)
    int head = blockIdx.y;           // 0..7
    int b  = widx >> 8;
    int w  = widx & 255;
    int wr = w >> 4, wc = w & 15;

    auto tokof = [&](int n) -> int {
        int si = (wr * WINSZ + (n >> 3) + 4) & 127;
        int sj = (wc * WINSZ + (n & 7) + 4) & 127;
        return b * LTOK + si * HW + sj;
    };

    {
        int i = wr * WINSZ + (lane >> 3);
        int j = wc * WINSZ + (lane & 7);
        int li = (i < 120) ? 0 : (i < 124 ? 1 : 2);
        int lj = (j < 120) ? 0 : (j < 124 ? 1 : 2);
        lbl[lane] = li * 3 + lj;
    }

    bf16x8 qf[4], kf[4];
    #pragma unroll
    for (int m = 0; m < 4; ++m) {
        int t = tokof(m * 16 + l15);
        const u16* base = qkv + (size_t)t * 768 + head * DH + hi * 8;
        qf[m] = *(const bf16x8*)base;           // q slice
        kf[m] = *(const bf16x8*)(base + 256);   // k slice
    }

    bf16x8 vf[2][2];
    #pragma unroll
    for (int ks = 0; ks < 2; ++ks) {
        #pragma unroll
        for (int i = 0; i < 8; ++i) {
            int t = tokof(ks * 32 + hi * 8 + i);
            const u16* vb = qkv + (size_t)t * 768 + 512 + head * DH;
            vf[0][ks][i] = (short)vb[l15];
            vf[1][ks][i] = (short)vb[16 + l15];
        }
    }

    f32x4 s[4][4];
    #pragma unroll
    for (int m = 0; m < 4; ++m)
        #pragma unroll
        for (int n = 0; n < 4; ++n) {
            f32x4 z = {0.f, 0.f, 0.f, 0.f};
            s[m][n] = __builtin_amdgcn_mfma_f32_16x16x32_bf16(qf[m], kf[n], z, 0, 0, 0);
        }

    __syncthreads();   // lbl visible

    int klbl[4];
    #pragma unroll
    for (int n = 0; n < 4; ++n) klbl[n] = lbl[n * 16 + l15];

    const float SCALE = 0.17677669529663687f;  // 1/sqrt(32)
    float inv[4][4];
    #pragma unroll
    for (int m = 0; m < 4; ++m) {
        #pragma unroll
        for (int r = 0; r < 4; ++r) {
            int q = m * 16 + hi * 4 + r;
            int qlbl = lbl[q];
            int rq = q >> 3, cq = q & 7;
            float v[4];
            #pragma unroll
            for (int n = 0; n < 4; ++n) {
                int kn = n * 16 + l15;
                int idx = (rq - (kn >> 3) + 7) * 15 + (cq - (kn & 7) + 7);
                float bv = bias_table[idx * HEADS + head];
                v[n] = s[m][n][r] * SCALE + bv + ((klbl[n] != qlbl) ? -100.f : 0.f);
            }
            float rmax = fmaxf(fmaxf(v[0], v[1]), fmaxf(v[2], v[3]));
            #pragma unroll
            for (int off = 1; off < 16; off <<= 1)
                rmax = fmaxf(rmax, __shfl_xor(rmax, off));
            float p0 = __expf(v[0] - rmax), p1 = __expf(v[1] - rmax);
            float p2 = __expf(v[2] - rmax), p3 = __expf(v[3] - rmax);
            float ls = p0 + p1 + p2 + p3;
            #pragma unroll
            for (int off = 1; off < 16; off <<= 1)
                ls += __shfl_xor(ls, off);
            inv[m][r] = 1.f / ls;
            int sw = (q & 7) << 3;
            P[q * NWIN + ((0 * 16 + l15) ^ sw)] = f2bf(p0);
            P[q * NWIN + ((1 * 16 + l15) ^ sw)] = f2bf(p1);
            P[q * NWIN + ((2 * 16 + l15) ^ sw)] = f2bf(p2);
            P[q * NWIN + ((3 * 16 + l15) ^ sw)] = f2bf(p3);
        }
    }

    __syncthreads();   // P visible

    f32x4 o[4][2] = {};
    #pragma unroll
    for (int ks = 0; ks < 2; ++ks) {
        #pragma unroll
        for (int m = 0; m < 4; ++m) {
            int row = m * 16 + l15;
            int colb = (ks * 32 + hi * 8) ^ ((row & 7) << 3);
            bf16x8 pa = *(const bf16x8*)&P[row * NWIN + colb];
            #pragma unroll
            for (int nf = 0; nf < 2; ++nf)
                o[m][nf] = __builtin_amdgcn_mfma_f32_16x16x32_bf16(
                    pa, vf[nf][ks], o[m][nf], 0, 0, 0);
        }
    }

    #pragma unroll
    for (int m = 0; m < 4; ++m) {
        #pragma unroll
        for (int r = 0; r < 4; ++r) {
            int q = m * 16 + hi * 4 + r;
            int t = tokof(q);
            u16* op = out + (size_t)t * CDIM + head * DH + l15;
            float iv = inv[m][r];
            op[0]  = f2bf(o[m][0][r] * iv);
            op[16] = f2bf(o[m][1][r] * iv);
        }
    }
}

// ---------------------------------------------------------------------------
// Depthwise 3x3 conv (NHWC, SAME zero-pad) + bias + GELU. bf16 in/out.
// ---------------------------------------------------------------------------
__global__ __launch_bounds__(256) void dwconv_kernel(
    const u16* __restrict__ h, const float* __restrict__ wt9,
    const float* __restrict__ bias, u16* __restrict__ out)
{
    int blk = blockIdx.x;             // b*2048 + i*16 + jt
    int b   = blk >> 11;
    int rem = blk & 2047;
    int i   = rem >> 4;
    int jt  = rem & 15;
    int cg  = (threadIdx.x & 127) * 8;           // channel base (0..1016)
    int j0  = jt * 8 + (threadIdx.x >> 7) * 4;   // first of 4 output pixels

    float acc[4][8] = {};
    const u16* base = h + (size_t)b * LTOK * HID + cg;

    #pragma unroll
    for (int di = 0; di < 3; ++di) {
        int ii = i + di - 1;
        if (ii < 0 || ii >= HW) continue;
        const u16* rowp = base + (size_t)ii * HW * HID;
        float v[6][8];
        #pragma unroll
        for (int cc = 0; cc < 6; ++cc) {
            int jj = j0 - 1 + cc;
            if (jj >= 0 && jj < HW) {
                ld8bf(&rowp[(size_t)jj * HID], v[cc]);
            } else {
                #pragma unroll
                for (int q = 0; q < 8; ++q) v[cc][q] = 0.f;
            }
        }
        #pragma unroll
        for (int t = 0; t < 3; ++t) {
            const float* wp = &wt9[(di * 3 + t) * HID + cg];
            float4 wa = *(const float4*)wp;
            float4 wb = *(const float4*)(wp + 4);
            float w[8] = {wa.x, wa.y, wa.z, wa.w, wb.x, wb.y, wb.z, wb.w};
            #pragma unroll
            for (int p = 0; p < 4; ++p)
                #pragma unroll
                for (int q = 0; q < 8; ++q)
                    acc[p][q] += v[p + t][q] * w[q];
        }
    }

    float4 ba = *(const float4*)&bias[cg];
    float4 bb = *(const float4*)&bias[cg + 4];
    float bs[8] = {ba.x, ba.y, ba.z, ba.w, bb.x, bb.y, bb.z, bb.w};
    u16* ob = out + ((size_t)b * LTOK + (size_t)i * HW + j0) * HID + cg;
    #pragma unroll
    for (int p = 0; p < 4; ++p) {
        u32 o[4];
        #pragma unroll
        for (int q = 0; q < 4; ++q) {
            u16 lo = f2bf(gelu_f(acc[p][2 * q] + bs[2 * q]));
            u16 hi = f2bf(gelu_f(acc[p][2 * q + 1] + bs[2 * q + 1]));
            o[q] = (u32)lo | ((u32)hi << 16);
        }
        *(uint4*)(ob + (size_t)p * HID) = make_uint4(o[0], o[1], o[2], o[3]);
    }
}

// ---------------------------------------------------------------------------
extern "C" void kernel_launch(void* const* d_in, const int* in_sizes, int n_in,
                              void* d_out, int out_size, void* d_ws, size_t ws_size,
                              hipStream_t stream) {
    const float* x      = (const float*)d_in[0];
    const float* n1g    = (const float*)d_in[1];
    const float* n1b    = (const float*)d_in[2];
    const float* qkv_w  = (const float*)d_in[3];
    const float* qkv_b  = (const float*)d_in[4];
    const float* relb   = (const float*)d_in[5];
    const float* proj_w = (const float*)d_in[6];
    const float* proj_b = (const float*)d_in[7];
    const float* n2g    = (const float*)d_in[8];
    const float* n2b    = (const float*)d_in[9];
    const float* lin1_w = (const float*)d_in[10];
    const float* lin1_b = (const float*)d_in[11];
    const float* dw_w   = (const float*)d_in[12];
    const float* dw_b   = (const float*)d_in[13];
    const float* lin2_w = (const float*)d_in[14];
    const float* lin2_b = (const float*)d_in[15];
    float* out = (float*)d_out;

    // bf16 arena (9*M8 elems = 151 MB, same as passing round 6):
    //  R0 [0,4M8):   yn -> attn -> yn2 -> h2[0:4M8)
    //  R1 [M8,4M8):  qkv -> lin1_wt
    //  R2 [4M8,5M8): x1 (steps 4-8)
    //  R3 [5M8,9M8): qkv_wt+proj_wt (steps 0-4) -> hbuf (6-7) -> lin2_wt (8)
    u16* ws16 = (u16*)d_ws;
    const size_t M8 = (size_t)MTOK * CDIM;   // 8,388,608
    u16* yn      = ws16;
    u16* qkv     = ws16 + M8;
    u16* attn    = ws16;
    u16* x1      = ws16 + 4 * M8;
    u16* yn2     = ws16;
    u16* hbuf    = ws16 + 5 * M8;
    u16* h2      = ws16;
    u16* qkv_wt  = ws16 + 5 * M8;            // [768][256]
    u16* proj_wt = qkv_wt + 768 * 256;       // [256][256]
    u16* lin1_wt = ws16 + M8;                // [1024][256]
    u16* lin2_wt = ws16 + 5 * M8;            // [256][1024]
    float* wt9   = (float*)d_out;            // [9][1024] scratch; d_out dead
                                             // until step 8 fully overwrites it

    // 0) weight prep (qkv, proj)
    transpose_bf16_kernel<<<dim3(768 / 32, 256 / 32), 256, 0, stream>>>(qkv_w, qkv_wt, 256, 768);
    transpose_bf16_kernel<<<dim3(256 / 32, 256 / 32), 256, 0, stream>>>(proj_w, proj_wt, 256, 256);
    // 1) LN1: fp32 in, bf16 out
    ln_kernel<float, u16><<<MTOK / 4, 256, 0, stream>>>(x, n1g, n1b, yn);
    // 2) qkv = yn @ qkv_w + qkv_b   (grid 6x256 = 1536, %8==0)
    mgemm_kernel<0, float, u16><<<(768 / 128) * (MTOK / 128), 256, 0, stream>>>(
        yn, qkv_wt, qkv_b, (const float*)nullptr, qkv, 768, CDIM, 768 / 128);
    // 3) windowed attention (MFMA)
    attn_mfma_kernel<<<dim3(512, HEADS), 64, 0, stream>>>(qkv, relb, attn);
    // weight prep (lin1) into R1 (qkv now dead); dw weights into d_out scratch
    transpose_bf16_kernel<<<dim3(1024 / 32, 256 / 32), 256, 0, stream>>>(lin1_w, lin1_wt, 256, 1024);
    dwprep_kernel<<<36, 256, 0, stream>>>(dw_w, wt9);
    // 4) x1 = attn @ proj_w + proj_b + x   (grid 2x256 = 512)
    mgemm_kernel<1, float, u16><<<(CDIM / 128) * (MTOK / 128), 256, 0, stream>>>(
        attn, proj_wt, proj_b, x, x1, CDIM, CDIM, CDIM / 128);
    // 5) LN2: bf16 in, bf16 out
    ln_kernel<u16, u16><<<MTOK / 4, 256, 0, stream>>>(x1, n2g, n2b, yn2);
    // 6) hbuf = gelu(yn2 @ lin1_w + lin1_b)   (grid 8x256 = 2048)
    mgemm_kernel<2, float, u16><<<(HID / 128) * (MTOK / 128), 256, 0, stream>>>(
        yn2, lin1_wt, lin1_b, (const float*)nullptr, hbuf, HID, CDIM, HID / 128);
    // 7) h2 = gelu(dwconv3x3(hbuf) + dw_b)
    dwconv_kernel<<<BATCH * 2048, 256, 0, stream>>>(hbuf, wt9, dw_b, h2);
    // weight prep (lin2) into R3 (hbuf now dead)
    transpose_bf16_kernel<<<dim3(256 / 32, 1024 / 32), 256, 0, stream>>>(lin2_w, lin2_wt, 1024, 256);
    // 8) out = h2 @ lin2_w + lin2_b + x1   (fp32 out, grid 2x256 = 512, K=1024)
    mgemm_kernel<1, u16, float><<<(CDIM / 128) * (MTOK / 128), 256, 0, stream>>>(
        h2, lin2_wt, lin2_b, x1, out, CDIM, HID, CDIM / 128);

    (void)in_sizes; (void)n_in; (void)out_size; (void)ws_size;
}